// Round 17
// baseline (200.214 us; speedup 1.0000x reference)
//
#include <hip/hip_runtime.h>

#define M_TOK 8192
#define N_OUT 4096
#define K_IN  4096

#define AS1 __attribute__((address_space(1)))
#define AS3 __attribute__((address_space(3)))

typedef __attribute__((ext_vector_type(4))) int i32x4;
typedef __attribute__((ext_vector_type(16))) int i32x16;

// inline-asm ds_read_b128: invisible to compiler AA; ordering is OURS via
// counted lgkmcnt + sched_barrier(0) (rule 18).
template <int OFF>
__device__ __forceinline__ i32x4 dsri(unsigned addr) {
    i32x4 r;
    asm volatile("ds_read_b128 %0, %1 offset:%2" : "=v"(r) : "v"(addr), "n"(OFF));
    return r;
}

// ---------------- prepass 1: per-token absmax quant of x (row-major out) ----

__global__ __launch_bounds__(256) void quant_x_kernel(
    const float* __restrict__ x, signed char* __restrict__ xq,
    float* __restrict__ tok_scale)
{
    const int row = blockIdx.x;
    const float4* xr = reinterpret_cast<const float4*>(x + (size_t)row * K_IN);
    const int t = threadIdx.x;
    float4 v[4];
    float m = 0.f;
#pragma unroll
    for (int i = 0; i < 4; ++i) {
        v[i] = xr[t + 256 * i];
        m = fmaxf(m, fmaxf(fmaxf(fabsf(v[i].x), fabsf(v[i].y)),
                           fmaxf(fabsf(v[i].z), fabsf(v[i].w))));
    }
#pragma unroll
    for (int off = 32; off >= 1; off >>= 1)
        m = fmaxf(m, __shfl_xor(m, off, 64));
    __shared__ float wmax[4];
    if ((t & 63) == 0) wmax[t >> 6] = m;
    __syncthreads();
    m = fmaxf(fmaxf(wmax[0], wmax[1]), fmaxf(wmax[2], wmax[3]));
    if (t == 0) tok_scale[row] = m * (1.0f / 127.0f);
    const float inv = (m > 0.f) ? (127.0f / m) : 0.f;
    int* xqi = reinterpret_cast<int*>(xq + (size_t)row * K_IN);
#pragma unroll
    for (int i = 0; i < 4; ++i) {
        const int q0 = __float2int_rn(v[i].x * inv) & 255;
        const int q1 = __float2int_rn(v[i].y * inv) & 255;
        const int q2 = __float2int_rn(v[i].z * inv) & 255;
        const int q3 = __float2int_rn(v[i].w * inv) & 255;
        xqi[t + 256 * i] = q0 | (q1 << 8) | (q2 << 16) | (q3 << 24);
    }
}

// ---------------- prepass 1b: retile xq8 row-major -> frag-tiled -------------

__global__ __launch_bounds__(256) void retile_x_kernel(
    const signed char* __restrict__ xq8, signed char* __restrict__ xqF)
{
    __shared__ __align__(16) char lds[32768];
    const int t = threadIdx.x;
    const int rb = blockIdx.x >> 2;
    const int kc = blockIdx.x & 3;

    const size_t srcBase = (size_t)rb * 32 * K_IN + (size_t)kc * 1024;
#pragma unroll
    for (int j = 0; j < 8; ++j) {
        const int u = j * 256 + t;
        const int row = u >> 6, gc = u & 63;
        const i32x4 v = *reinterpret_cast<const i32x4*>(
            xq8 + srcBase + (size_t)row * K_IN + gc * 16);
        *reinterpret_cast<i32x4*>(
            lds + ((row * 64 + (gc ^ (row & 7))) * 16)) = v;
    }
    __syncthreads();

    const int l = t & 63;
    const int W = t >> 6;
    const int row = l & 31;
    const int hi = l >> 5;
    i32x4* dst0 = reinterpret_cast<i32x4*>(xqF) +
                  ((size_t)rb * 128 + kc * 32) * 64 + l;
#pragma unroll
    for (int i = 0; i < 8; ++i) {
        const int kfl = W * 8 + i;
        const int gc = (kfl * 2 + hi) ^ (row & 7);
        const i32x4 v = *reinterpret_cast<const i32x4*>(
            lds + ((row * 64 + gc) * 16));
        dst0[(size_t)kfl * 64] = v;
    }
}

// ---------------- prepass 2: pack Wq int32 -> int8, frag-tiled ---------------

__global__ __launch_bounds__(256) void pack_w_frag_kernel(
    const int* __restrict__ wq, signed char* __restrict__ wqF)
{
    const int t = threadIdx.x;
    const int l = t & 63;
    const int W = t >> 6;
    const int rb = blockIdx.x >> 3;
    const int pc = blockIdx.x & 7;
    const int r = rb * 32 + (l & 31);
    const int4* wr4 = reinterpret_cast<const int4*>(wq) + (size_t)r * 1024;
    i32x4* outF = reinterpret_cast<i32x4*>(wqF) + (size_t)rb * 128 * 64 + l;
#pragma unroll
    for (int q = 0; q < 4; ++q) {
        const int f = W + 4 * (pc * 4 + q);
        const int c4 = f * 8 + (l >> 5) * 4;
        i32x4 o;
#pragma unroll
        for (int j = 0; j < 4; ++j) {
            const int4 a = wr4[c4 + j];
            o[j] = (a.x & 255) | ((a.y & 255) << 8) | ((a.z & 255) << 16) | ((a.w & 255) << 24);
        }
        outF[(size_t)f * 64] = o;
    }
}

// ------- int8 GEMM R17: A via LDS (32KB, ring-4), B DIRECT-TO-REG v2 ---------
// R9-R16: body = MFMA(585) + LDS-port(~680) in series. Can't overlap them ->
// shrink the LDS term: B off LDS entirely (removes 16 reads + 8 writes/CU/
// tile) -> LDS ~480 cyc < MFMA 585.
// R11 failed because its boundary vmcnt drained B loads issued 1/2 body
// earlier. v2 FIFO (op-exact, g=1 op, b=2 ops; per body issues g(T+3),
// b(T+2)): entry vmcnt(3) drains b(T) [issued 2 bodies ago]; boundary
// vmcnt(5) drains g(T+2) only. B triple-buffered R/S/U (period 3), A sets
// X/Y (period 2) -> 6-body unroll. Tail: body 125 VMB=4; 126 VME=2,VMB=2;
// GFINAL entry vmcnt(0). Prologue vmcnt(2) fully drains b(0) (7-op FIFO).
// WAR: g(T+3) writes A slot (T-1)&3; tile T-1 A reads drained by body T-1's
// lgkm(4) + its barrier. lgkm: entry lgkm(2) [A0,A1(T)], mid lgkm(4) [A2,A3].

#define NKT 128            // K tiles of 32
#define SLOTA 8192         // 8 A frags x 1KB

#define MFMA(a, b, c) c = __builtin_amdgcn_mfma_i32_32x32x32_i8(a, b, c, 0, 0, 0)

// 4 A reads for one tile: frags mb=0..3 at (wr*4+mb)*1024 (base handles wr)
#define RD4(P, aA)                              \
    P##_A0 = dsri<0>(aA);                       \
    P##_A1 = dsri<1024>(aA);                    \
    P##_A2 = dsri<2048>(aA);                    \
    P##_A3 = dsri<3072>(aA);

// 2 B frag loads (plain C++ -> global_load_dwordx4; pinned between the
// surrounding "memory" asms)
#define RDB(P, TT)                                       \
    P##_B0 = bSrc[(size_t)(TT) * 64];                    \
    P##_B1 = bSrc[(size_t)(128 + (TT)) * 64];

#define CL4a(PA, PB)                                                \
    MFMA(PA##_A0, PB##_B0, acc00); MFMA(PA##_A0, PB##_B1, acc01);   \
    MFMA(PA##_A1, PB##_B0, acc10); MFMA(PA##_A1, PB##_B1, acc11);

#define CL4b(PA, PB)                                                \
    MFMA(PA##_A2, PB##_B0, acc20); MFMA(PA##_A2, PB##_B1, acc21);   \
    MFMA(PA##_A3, PB##_B0, acc30); MFMA(PA##_A3, PB##_B1, acc31);

#define GBODY(T, CA, NA, CB, NB, DO_G, DO_B, VME, VMB)                    \
    {                                                                     \
        asm volatile("s_waitcnt vmcnt(" #VME ")" ::: "memory");           \
        __builtin_amdgcn_sched_barrier(0);                                \
        asm volatile("s_waitcnt lgkmcnt(2)" ::: "memory");                \
        __builtin_amdgcn_sched_barrier(0);                                \
        __builtin_amdgcn_s_setprio(1);                                    \
        CL4a(CA, CB)                                                      \
        __builtin_amdgcn_s_setprio(0);                                    \
        __builtin_amdgcn_sched_barrier(0);                                \
        const unsigned aN_ = aBase + (unsigned)((((T) + 1) & 3) * SLOTA); \
        RD4(NA, aN_)                                                      \
        if (DO_G) stageA((T) + 3);                                        \
        if (DO_B) { RDB(NB, (T) + 2) }                                    \
        asm volatile("s_waitcnt lgkmcnt(4)" ::: "memory");                \
        __builtin_amdgcn_sched_barrier(0);                                \
        __builtin_amdgcn_s_setprio(1);                                    \
        CL4b(CA, CB)                                                      \
        __builtin_amdgcn_s_setprio(0);                                    \
        __builtin_amdgcn_sched_barrier(0);                                \
        asm volatile("s_waitcnt vmcnt(" #VMB ")" ::: "memory");           \
        __builtin_amdgcn_sched_barrier(0);                                \
        __builtin_amdgcn_s_barrier();                                     \
        __builtin_amdgcn_sched_barrier(0);                                \
    }

#define GFINAL(CA, CB)                                                    \
    {                                                                     \
        asm volatile("s_waitcnt vmcnt(0)" ::: "memory");                  \
        __builtin_amdgcn_sched_barrier(0);                                \
        asm volatile("s_waitcnt lgkmcnt(2)" ::: "memory");                \
        __builtin_amdgcn_sched_barrier(0);                                \
        __builtin_amdgcn_s_setprio(1);                                    \
        CL4a(CA, CB)                                                      \
        __builtin_amdgcn_s_setprio(0);                                    \
        asm volatile("s_waitcnt lgkmcnt(0)" ::: "memory");                \
        __builtin_amdgcn_sched_barrier(0);                                \
        __builtin_amdgcn_s_setprio(1);                                    \
        CL4b(CA, CB)                                                      \
        __builtin_amdgcn_s_setprio(0);                                    \
        __builtin_amdgcn_sched_barrier(0);                                \
    }

__global__ __launch_bounds__(512, 2) void qgemm_i8bd_kernel(
    const signed char* __restrict__ xqF,
    const signed char* __restrict__ wqF,
    const float* __restrict__ tok_scale,
    const float* __restrict__ row_scales,
    const float* __restrict__ bias,
    float* __restrict__ out)
{
    __shared__ __align__(16) char smem[4 * SLOTA];   // A only: 32 KiB, ring-4

    const int tid = threadIdx.x;
    const int l = tid & 63;
    const int w = tid >> 6;      // 0..7
    const int wr = w >> 2;       // 0..1
    const int wc = w & 3;        // 0..3

    // XCD-aware bijective swizzle (nwg = 512, 512 % 8 == 0)
    const int bid = blockIdx.x;
    const int swz = (bid & 7) * 64 + (bid >> 3);
    const int bm = swz >> 4;     // 0..31
    const int bn = swz & 15;     // 0..15

    // ---- A staging: wave w stages A frag w (1KB contiguous) per tile ----
    const signed char* aS = xqF + ((size_t)(bm * 8 + w) * 128) * 1024 + (size_t)l * 16;
    char* aDst = smem + w * 1024;

    auto stageA = [&](int tt) {
        __builtin_amdgcn_global_load_lds(
            (const AS1 void*)(aS + (size_t)tt * 1024),
            (AS3 void*)(aDst + (tt & 3) * SLOTA), 16, 0, 0);
    };

    // ---- B direct-to-reg: wave (wc) owns B row-blocks bn*8 + wc*2 + {0,1} ----
    // frag (rb, kf) at (rb*128 + kf) * 64 i32x4-units; per-lane +l.
    const i32x4* bSrc = reinterpret_cast<const i32x4*>(
        wqF + ((size_t)(bn * 8 + wc * 2) * 128) * 1024) + l;

    // ---- fragment-linear A ds_read base ----
    const unsigned sbase = (unsigned)(uintptr_t)(AS3 char*)smem;
    const unsigned aBase = sbase + (unsigned)(wr * 4096 + l * 16);  // + slot + mb*1024

    i32x16 acc00 = {0}, acc01 = {0}, acc10 = {0}, acc11 = {0};
    i32x16 acc20 = {0}, acc21 = {0}, acc30 = {0}, acc31 = {0};

    i32x4 X_A0, X_A1, X_A2, X_A3;
    i32x4 Y_A0, Y_A1, Y_A2, Y_A3;
    i32x4 R_B0, R_B1, S_B0, S_B1, U_B0, U_B1;

    // ---- prologue ----
    // FIFO: g0,g1,g2,b0(2),b1(2) = 7 ops. vmcnt(2) drains g0,g1,g2,b0 fully
    // (leaves b1's 2 ops) -- body 0 needs A slots 0,1 and B set R = b(0).
    stageA(0); stageA(1); stageA(2);
    RDB(R, 0)
    RDB(S, 1)
    asm volatile("s_waitcnt vmcnt(2)" ::: "memory");
    __builtin_amdgcn_sched_barrier(0);
    __builtin_amdgcn_s_barrier();
    __builtin_amdgcn_sched_barrier(0);
    RD4(X, aBase)                   // A tile 0 (slot 0)

    // ---- main loop: bodies 0..119, 6-body unroll (A period 2 x B period 3) ----
    for (int t = 0; t < 120; t += 6) {
        GBODY(t + 0, X, Y, R, U, true, true, 3, 5);
        GBODY(t + 1, Y, X, S, R, true, true, 3, 5);
        GBODY(t + 2, X, Y, U, S, true, true, 3, 5);
        GBODY(t + 3, Y, X, R, U, true, true, 3, 5);
        GBODY(t + 4, X, Y, S, R, true, true, 3, 5);
        GBODY(t + 5, Y, X, U, S, true, true, 3, 5);
    }
    // tail: bodies 120..126 explicit, then final tile 127
    GBODY(120, X, Y, R, U, true,  true,  3, 5);   // g(123), b(122)
    GBODY(121, Y, X, S, R, true,  true,  3, 5);   // g(124), b(123)
    GBODY(122, X, Y, U, S, true,  true,  3, 5);   // g(125), b(124)
    GBODY(123, Y, X, R, U, true,  true,  3, 5);   // g(126), b(125)
    GBODY(124, X, Y, S, R, true,  true,  3, 5);   // g(127), b(126)
    GBODY(125, Y, X, U, S, false, true,  3, 4);   // b(127); drain g(127)
    GBODY(126, X, Y, R, R, false, false, 2, 2);   // drain b(126)
    GFINAL(Y, S)                                  // tile 127: A=Y, B set S

    // ---- epilogue: dequant (tok_scale via global, L2-hot), store ----
    const int cl = l & 31;
    const int rg4 = (l >> 5) * 4;
    const int gcol0 = bn * 256 + wc * 64;
    const float* tsrow = tok_scale + bm * 256 + wr * 128;
    float cs[2], bb[2];
#pragma unroll
    for (int nb = 0; nb < 2; ++nb) {
        const int col = gcol0 + nb * 32 + cl;
        cs[nb] = row_scales[col] * (1.0f / 127.0f);
        bb[nb] = bias[col];
    }
    const i32x16* accs[4][2] = {{&acc00, &acc01}, {&acc10, &acc11},
                                {&acc20, &acc21}, {&acc30, &acc31}};
#pragma unroll
    for (int mb = 0; mb < 4; ++mb) {
#pragma unroll
        for (int reg = 0; reg < 16; ++reg) {
            const int rl = mb * 32 + (reg & 3) + 8 * (reg >> 2) + rg4;
            const float tsv = tsrow[rl];
            float* orow = out + (size_t)(bm * 256 + wr * 128 + rl) * N_OUT + gcol0 + cl;
#pragma unroll
            for (int nb = 0; nb < 2; ++nb) {
                const int a = (*accs[mb][nb])[reg];
                orow[nb * 32] = (float)a * tsv * cs[nb] + bb[nb];
            }
        }
    }
}

// ---------------- launch ----------------

extern "C" void kernel_launch(void* const* d_in, const int* in_sizes, int n_in,
                              void* d_out, int out_size, void* d_ws, size_t ws_size,
                              hipStream_t stream) {
    const float* x = (const float*)d_in[0];
    const int* wq = (const int*)d_in[1];
    const float* row_scales = (const float*)d_in[2];
    const float* bias = (const float*)d_in[3];
    float* out = (float*)d_out;

    signed char* xq8 = (signed char*)d_ws;                       // 32 MiB row-major
    signed char* xqF = xq8 + (size_t)M_TOK * K_IN;               // 32 MiB frag-tiled
    signed char* wqF = xqF + (size_t)M_TOK * K_IN;               // 16 MiB frag-tiled
    float* tok_scale = (float*)(wqF + (size_t)N_OUT * K_IN);     // 32 KiB
    (void)ws_size;

    quant_x_kernel<<<M_TOK, 256, 0, stream>>>(x, xq8, tok_scale);
    pack_w_frag_kernel<<<1024, 256, 0, stream>>>(wq, wqF);
    retile_x_kernel<<<1024, 256, 0, stream>>>(xq8, xqF);

    const int nblocks = (M_TOK / 256) * (N_OUT / 256);  // 512
    qgemm_i8bd_kernel<<<nblocks, 512, 0, stream>>>(
        xqF, wqF, tok_scale, row_scales, bias, out);
}